// Round 1
// baseline (363.250 us; speedup 1.0000x reference)
//
#include <hip/hip_runtime.h>
#include <math.h>

// ---------------------------------------------------------------------------
// QCNN 8-qubit statevector sim, wave-per-batch-element.
// Amp index f (0..255): qubit w <-> bit (7-w)  (reference is MSB-first).
// Physical layout: f = (lane << 2) | r  -> qubits 6,7 are register bits (r),
// qubits 0..5 are lane bits (lane bit 5-w).
// ---------------------------------------------------------------------------

struct c32 { float x, y; };

__device__ __forceinline__ c32 cmul(c32 a, c32 b) {
    return c32{a.x * b.x - a.y * b.y, a.x * b.y + a.y * b.x};
}
__device__ __forceinline__ c32 cadd(c32 a, c32 b) { return c32{a.x + b.x, a.y + b.y}; }

// ---- ws layout (floats) ----
// [0..23]    cos/sin of conv_rz[cc]/2   (cc = 0..11)
// [24..47]   cos/sin of conv_ry[cc]/2
// [48..71]   cos/sin of conv_ry2[cc]/2
// [72..119]  pool U3 matrices: 6 x {u00.re,im, u01.re,im, u10.re,im, u11.re,im}
__global__ void qcnn_precompute(const float* __restrict__ conv_rz,
                                const float* __restrict__ conv_ry,
                                const float* __restrict__ conv_ry2,
                                const float* __restrict__ pool,
                                float* __restrict__ ws) {
    int t = threadIdx.x;
    if (t < 12) {
        float h;
        h = 0.5f * conv_rz[t];  ws[2 * t]      = cosf(h); ws[2 * t + 1]      = sinf(h);
        h = 0.5f * conv_ry[t];  ws[24 + 2 * t] = cosf(h); ws[24 + 2 * t + 1] = sinf(h);
        h = 0.5f * conv_ry2[t]; ws[48 + 2 * t] = cosf(h); ws[48 + 2 * t + 1] = sinf(h);
    }
    if (t < 6) {
        float th = pool[3 * t], ph = pool[3 * t + 1], la = pool[3 * t + 2];
        float ct = cosf(0.5f * th), st = sinf(0.5f * th);
        float* w = ws + 72 + 8 * t;
        w[0] = ct;                 w[1] = 0.f;                 // u00
        w[2] = -cosf(la) * st;     w[3] = -sinf(la) * st;      // u01 = -e^{i la} st
        w[4] = cosf(ph) * st;      w[5] = sinf(ph) * st;       // u10 = e^{i ph} st
        w[6] = cosf(ph + la) * ct; w[7] = sinf(ph + la) * ct;  // u11 = e^{i(ph+la)} ct
    }
}

// RZ(theta) = diag(e^{-i t/2}, e^{+i t/2}); pass c = cos(t/2), sn = sin(t/2).
template <int W>
__device__ __forceinline__ void apply_rz(c32 s[4], int lane, float c, float sn) {
    constexpr int pos = 7 - W;
#pragma unroll
    for (int r = 0; r < 4; ++r) {
        int bit;
        if constexpr (pos < 2) bit = (r >> pos) & 1;
        else                   bit = (lane >> (pos - 2)) & 1;
        float im = bit ? sn : -sn;
        s[r] = cmul(s[r], c32{c, im});
    }
}

// RY(theta) = [[c,-s],[s,c]]; pass c = cos(t/2), sn = sin(t/2).
template <int W>
__device__ __forceinline__ void apply_ry(c32 s[4], int lane, float c, float sn) {
    constexpr int pos = 7 - W;
    if constexpr (pos < 2) {
        constexpr int m = 1 << pos;
#pragma unroll
        for (int r = 0; r < 4; ++r) {
            if (!(r & m)) {
                c32 a = s[r], b = s[r | m];
                s[r]     = c32{c * a.x - sn * b.x, c * a.y - sn * b.y};
                s[r | m] = c32{sn * a.x + c * b.x, sn * a.y + c * b.y};
            }
        }
    } else {
        constexpr int lm = 1 << (pos - 2);
        int bit = (lane >> (pos - 2)) & 1;
        float cp = bit ? sn : -sn;   // coeff of partner amp
#pragma unroll
        for (int r = 0; r < 4; ++r) {
            c32 p{__shfl_xor(s[r].x, lm), __shfl_xor(s[r].y, lm)};
            s[r] = c32{c * s[r].x + cp * p.x, c * s[r].y + cp * p.y};
        }
    }
}

template <int W>
__device__ __forceinline__ void apply_u3(c32 s[4], int lane, c32 u00, c32 u01, c32 u10, c32 u11) {
    constexpr int pos = 7 - W;
    if constexpr (pos < 2) {
        constexpr int m = 1 << pos;
#pragma unroll
        for (int r = 0; r < 4; ++r) {
            if (!(r & m)) {
                c32 a = s[r], b = s[r | m];
                s[r]     = cadd(cmul(u00, a), cmul(u01, b));
                s[r | m] = cadd(cmul(u10, a), cmul(u11, b));
            }
        }
    } else {
        constexpr int lm = 1 << (pos - 2);
        int bit = (lane >> (pos - 2)) & 1;
        c32 cM = bit ? u11 : u00;
        c32 cP = bit ? u10 : u01;
#pragma unroll
        for (int r = 0; r < 4; ++r) {
            c32 p{__shfl_xor(s[r].x, lm), __shfl_xor(s[r].y, lm)};
            s[r] = cadd(cmul(cM, s[r]), cmul(cP, p));
        }
    }
}

// CX: flip target bit where control bit = 1.
template <int C, int T>
__device__ __forceinline__ void apply_cx(c32 s[4], int lane) {
    constexpr int cp = 7 - C, tp = 7 - T;
    if constexpr (cp < 2 && tp < 2) {
        constexpr int cm = 1 << cp, tm = 1 << tp;
        c32 ns[4];
#pragma unroll
        for (int r = 0; r < 4; ++r) ns[r] = (r & cm) ? s[r ^ tm] : s[r];
#pragma unroll
        for (int r = 0; r < 4; ++r) s[r] = ns[r];
    } else if constexpr (cp < 2) {      // control register bit, target lane bit
        constexpr int cm = 1 << cp, tlm = 1 << (tp - 2);
#pragma unroll
        for (int r = 0; r < 4; ++r) {
            if (r & cm) {
                s[r].x = __shfl_xor(s[r].x, tlm);
                s[r].y = __shfl_xor(s[r].y, tlm);
            }
        }
    } else if constexpr (tp < 2) {      // control lane bit, target register bit
        constexpr int tm = 1 << tp;
        int cb = (lane >> (cp - 2)) & 1;
        c32 ns[4];
#pragma unroll
        for (int r = 0; r < 4; ++r) ns[r] = cb ? s[r ^ tm] : s[r];
#pragma unroll
        for (int r = 0; r < 4; ++r) s[r] = ns[r];
    } else {                            // both lane bits
        constexpr int tlm = 1 << (tp - 2);
        int cb = (lane >> (cp - 2)) & 1;
#pragma unroll
        for (int r = 0; r < 4; ++r) {
            float px = __shfl_xor(s[r].x, tlm);
            float py = __shfl_xor(s[r].y, tlm);
            s[r].x = cb ? px : s[r].x;
            s[r].y = cb ? py : s[r].y;
        }
    }
}

#define RSQ2 0.70710678118654752f

#define CONV(Q0, Q1, CC) do {                                               \
    apply_rz<Q1>(s, lane, RSQ2, -RSQ2);              /* RZ(-pi/2) on q1 */  \
    apply_cx<Q1, Q0>(s, lane);                                              \
    apply_rz<Q0>(s, lane, wsp[2*(CC)], wsp[2*(CC)+1]);                      \
    apply_ry<Q1>(s, lane, wsp[24+2*(CC)], wsp[24+2*(CC)+1]);                \
    apply_cx<Q0, Q1>(s, lane);                                              \
    apply_ry<Q1>(s, lane, wsp[48+2*(CC)], wsp[48+2*(CC)+1]);                \
    apply_cx<Q1, Q0>(s, lane);                                              \
    apply_rz<Q0>(s, lane, RSQ2, RSQ2);               /* RZ(+pi/2) on q0 */  \
} while (0)

#define POOL(Q, PC) do {                                                    \
    const float* u = wsp + 72 + 8 * (PC);                                   \
    apply_u3<Q>(s, lane, c32{u[0], u[1]}, c32{u[2], u[3]},                  \
                c32{u[4], u[5]}, c32{u[6], u[7]});                          \
} while (0)

__device__ __forceinline__ float tanh_fast(float x) {
    float e = __expf(2.f * x);
    return (e - 1.f) / (e + 1.f);
}

__launch_bounds__(256)
__global__ void qcnn_main(const float* __restrict__ x,
                          const float* __restrict__ wsp,
                          const float* __restrict__ W1,
                          const float* __restrict__ b1,
                          const float* __restrict__ W2,
                          const float* __restrict__ b2,
                          float* __restrict__ out, int B) {
    int gid  = blockIdx.x * blockDim.x + threadIdx.x;
    int b    = gid >> 6;
    int lane = threadIdx.x & 63;
    if (b >= B) return;

    // --- angle encoding: product state ---
    const float* xb = x + b * 8;
    float cw[8], sw[8];
#pragma unroll
    for (int w = 0; w < 8; ++w) {
        float h = 0.5f * xb[w];
        cw[w] = __cosf(h);
        sw[w] = __sinf(h);
    }
    // lane bits cover qubits 0..5 (qubit w -> lane bit 5-w)
    float prodLane = 1.f;
#pragma unroll
    for (int w = 0; w < 6; ++w)
        prodLane *= ((lane >> (5 - w)) & 1) ? sw[w] : cw[w];

    c32 s[4];
#pragma unroll
    for (int r = 0; r < 4; ++r) {
        float a = prodLane * ((r & 2) ? sw[6] : cw[6]) * ((r & 1) ? sw[7] : cw[7]);
        s[r] = c32{a, 0.f};
    }

    // --- layer 0: pairs (0,1)(2,3)(4,5)(6,7) then (1,2)(3,4)(5,6) ---
    CONV(0, 1, 0); CONV(2, 3, 1); CONV(4, 5, 2); CONV(6, 7, 3);
    CONV(1, 2, 4); CONV(3, 4, 5); CONV(5, 6, 6);
    POOL(1, 0); POOL(3, 1); POOL(5, 2); POOL(7, 3);

    // --- layer 1: active = [1,3,5,7]; pairs (1,3)(5,7) then (3,5) ---
    CONV(1, 3, 7); CONV(5, 7, 8); CONV(3, 5, 9);
    POOL(3, 4); POOL(7, 5);

    // --- expvals: Z on qubit 3 (lane bit 2) and qubit 7 (r bit 0) ---
    float e3 = 0.f, e7 = 0.f;
#pragma unroll
    for (int r = 0; r < 4; ++r) {
        float p = s[r].x * s[r].x + s[r].y * s[r].y;
        e7 += (r & 1) ? -p : p;
        e3 += p;
    }
    e3 = ((lane >> 2) & 1) ? -e3 : e3;
#pragma unroll
    for (int m = 1; m < 64; m <<= 1) {
        e3 += __shfl_xor(e3, m);
        e7 += __shfl_xor(e7, m);
    }

    // --- MLP head: h = tanh([e3,e7] @ W1^T + b1); out = sigmoid(h @ W2^T + b2) ---
    float z = b2[0];
#pragma unroll
    for (int i = 0; i < 10; ++i) {
        float h = tanh_fast(W1[2 * i] * e3 + W1[2 * i + 1] * e7 + b1[i]);
        z += W2[i] * h;
    }
    float o = 1.f / (1.f + __expf(-z));
    if (lane == 0) out[b] = o;
}

extern "C" void kernel_launch(void* const* d_in, const int* in_sizes, int n_in,
                              void* d_out, int out_size, void* d_ws, size_t ws_size,
                              hipStream_t stream) {
    const float* x       = (const float*)d_in[0];
    const float* conv_rz = (const float*)d_in[1];
    const float* conv_ry = (const float*)d_in[2];
    const float* conv_ry2= (const float*)d_in[3];
    const float* pool    = (const float*)d_in[4];
    const float* W1      = (const float*)d_in[5];
    const float* b1      = (const float*)d_in[6];
    const float* W2      = (const float*)d_in[7];
    const float* b2      = (const float*)d_in[8];
    float* out = (float*)d_out;
    float* ws  = (float*)d_ws;

    int B = in_sizes[0] / 8;

    qcnn_precompute<<<1, 64, 0, stream>>>(conv_rz, conv_ry, conv_ry2, pool, ws);

    int threads = 256;                      // 4 waves/block, 1 element/wave
    int blocks  = (B * 64 + threads - 1) / threads;
    qcnn_main<<<blocks, threads, 0, stream>>>(x, ws, W1, b1, W2, b2, out, B);
}

// Round 3
// 219.844 us; speedup vs baseline: 1.6523x; 1.6523x over previous
//
#include <hip/hip_runtime.h>
#include <math.h>

// ---------------------------------------------------------------------------
// QCNN 8-qubit statevector sim, wave-per-batch-element, v3.
// Layout: amp = (lane bits, 2 reg bits). Placement chosen by gate traffic:
//   q7 -> reg bit 0, q3 -> reg bit 1      (hot qubits + final observables)
//   q4 -> lane mask 1  (DPP quad_perm)    q6 -> lane mask 2  (DPP quad_perm)
//   q2 -> lane mask 4  (ds_swizzle)       q0 -> lane mask 8  (ds_swizzle)
//   q1 -> lane mask 16 (ds_swizzle)       q5 -> lane mask 32 (__shfl_xor)
// All parameters delivered via lane-distributed VGPRs + v_readlane (no loads
// in the gate chain).
// ---------------------------------------------------------------------------

struct c32 { float x, y; };

__host__ __device__ constexpr int LM(int w) {
    return w==0?8 : w==1?16 : w==2?4 : w==4?1 : w==5?32 : w==6?2 : 0;
}
__host__ __device__ constexpr int RB(int w) { return w==7?1 : w==3?2 : 0; }

// xor-shuffle across lanes, mask M.
template<int M>
__device__ __forceinline__ float shflx(float v) {
    if constexpr (M == 1) {        // quad_perm [1,0,3,2]
        return __int_as_float(__builtin_amdgcn_update_dpp(
            __float_as_int(v), __float_as_int(v), 0xB1, 0xF, 0xF, false));
    } else if constexpr (M == 2) { // quad_perm [2,3,0,1]
        return __int_as_float(__builtin_amdgcn_update_dpp(
            __float_as_int(v), __float_as_int(v), 0x4E, 0xF, 0xF, false));
    } else if constexpr (M == 4) {
        return __int_as_float(__builtin_amdgcn_ds_swizzle(__float_as_int(v), 0x101F));
    } else if constexpr (M == 8) {
        return __int_as_float(__builtin_amdgcn_ds_swizzle(__float_as_int(v), 0x201F));
    } else if constexpr (M == 16) {
        return __int_as_float(__builtin_amdgcn_ds_swizzle(__float_as_int(v), 0x401F));
    } else {                       // M == 32: known-good cross-half shuffle
        return __shfl_xor(v, 32);
    }
}

__device__ __forceinline__ float wave_sum(float v) {
    v += shflx<1>(v); v += shflx<2>(v); v += shflx<4>(v);
    v += shflx<8>(v); v += shflx<16>(v);
    v += __shfl_xor(v, 32);
    return v;
}

// RZ(theta): bit0 amps *= (c - i sn), bit1 amps *= (c + i sn)
template<int W>
__device__ __forceinline__ void rz_param(c32 s[4], int lane, float c, float sn) {
    if constexpr (RB(W) != 0) {
        constexpr int m = RB(W);
#pragma unroll
        for (int r = 0; r < 4; ++r) {
            float im = (r & m) ? sn : -sn;   // compile-time sign
            float nx = c * s[r].x - im * s[r].y;
            float ny = c * s[r].y + im * s[r].x;
            s[r].x = nx; s[r].y = ny;
        }
    } else {
        constexpr int m = LM(W);
        float im = (lane & m) ? sn : -sn;
#pragma unroll
        for (int r = 0; r < 4; ++r) {
            float nx = c * s[r].x - im * s[r].y;
            float ny = c * s[r].y + im * s[r].x;
            s[r].x = nx; s[r].y = ny;
        }
    }
}

// Fixed RZ(-pi/2) ~ diag(1,-i)  (PLUS=false);  RZ(+pi/2) ~ diag(1,+i) (PLUS=true)
// (equal up to a state-global phase -> expvals unchanged)
template<int W, bool PLUS>
__device__ __forceinline__ void sdiag(c32 s[4], int lane) {
    if constexpr (RB(W) != 0) {
        constexpr int m = RB(W);
#pragma unroll
        for (int r = 0; r < 4; ++r) {
            if (r & m) {
                float t = s[r].x;
                if constexpr (PLUS) { s[r].x = -s[r].y; s[r].y =  t; }
                else                { s[r].x =  s[r].y; s[r].y = -t; }
            }
        }
    } else {
        constexpr int m = LM(W);
        const bool bit = (lane & m) != 0;
#pragma unroll
        for (int r = 0; r < 4; ++r) {
            float sx = PLUS ? -s[r].y :  s[r].y;
            float sy = PLUS ?  s[r].x : -s[r].x;
            float nx = bit ? sx : s[r].x;
            float ny = bit ? sy : s[r].y;
            s[r].x = nx; s[r].y = ny;
        }
    }
}

// RY(theta) = [[c,-s],[s,c]]
template<int W>
__device__ __forceinline__ void ry(c32 s[4], int lane, float c, float sn) {
    if constexpr (RB(W) != 0) {
        constexpr int m = RB(W);
#pragma unroll
        for (int r = 0; r < 4; ++r) {
            if (!(r & m)) {
                c32 a = s[r], b = s[r | m];
                s[r].x     = c * a.x - sn * b.x;  s[r].y     = c * a.y - sn * b.y;
                s[r | m].x = sn * a.x + c * b.x;  s[r | m].y = sn * a.y + c * b.y;
            }
        }
    } else {
        constexpr int m = LM(W);
        float cp = (lane & m) ? sn : -sn;
#pragma unroll
        for (int r = 0; r < 4; ++r) {
            float px = shflx<m>(s[r].x);
            float py = shflx<m>(s[r].y);
            s[r].x = c * s[r].x + cp * px;
            s[r].y = c * s[r].y + cp * py;
        }
    }
}

template<int W>
__device__ __forceinline__ void u3g(c32 s[4], int lane, c32 u00, c32 u01, c32 u10, c32 u11) {
    if constexpr (RB(W) != 0) {
        constexpr int m = RB(W);
#pragma unroll
        for (int r = 0; r < 4; ++r) {
            if (!(r & m)) {
                c32 a = s[r], b = s[r | m];
                float nx0 = u00.x*a.x - u00.y*a.y + u01.x*b.x - u01.y*b.y;
                float ny0 = u00.x*a.y + u00.y*a.x + u01.x*b.y + u01.y*b.x;
                float nx1 = u10.x*a.x - u10.y*a.y + u11.x*b.x - u11.y*b.y;
                float ny1 = u10.x*a.y + u10.y*a.x + u11.x*b.y + u11.y*b.x;
                s[r]     = c32{nx0, ny0};
                s[r | m] = c32{nx1, ny1};
            }
        }
    } else {
        constexpr int m = LM(W);
        const bool bit = (lane & m) != 0;
        c32 cM, cP;
        cM.x = bit ? u11.x : u00.x;  cM.y = bit ? u11.y : u00.y;
        cP.x = bit ? u10.x : u01.x;  cP.y = bit ? u10.y : u01.y;
#pragma unroll
        for (int r = 0; r < 4; ++r) {
            float px = shflx<m>(s[r].x);
            float py = shflx<m>(s[r].y);
            float nx = cM.x*s[r].x - cM.y*s[r].y + cP.x*px - cP.y*py;
            float ny = cM.x*s[r].y + cM.y*s[r].x + cP.x*py + cP.y*px;
            s[r].x = nx; s[r].y = ny;
        }
    }
}

// CNOT: flip target where control = 1
template<int C, int T>
__device__ __forceinline__ void cx(c32 s[4], int lane) {
    if constexpr (RB(C) != 0 && RB(T) != 0) {
        constexpr int cm = RB(C), tm = RB(T);
        c32 ns[4];
#pragma unroll
        for (int r = 0; r < 4; ++r) ns[r] = (r & cm) ? s[r ^ tm] : s[r];
#pragma unroll
        for (int r = 0; r < 4; ++r) s[r] = ns[r];
    } else if constexpr (RB(C) != 0) {          // reg control, lane target
        constexpr int cm = RB(C), tm = LM(T);
#pragma unroll
        for (int r = 0; r < 4; ++r)
            if (r & cm) { s[r].x = shflx<tm>(s[r].x); s[r].y = shflx<tm>(s[r].y); }
    } else if constexpr (RB(T) != 0) {          // lane control, reg target
        constexpr int cm = LM(C), tm = RB(T);
        const bool cb = (lane & cm) != 0;
        c32 ns[4];
#pragma unroll
        for (int r = 0; r < 4; ++r) {
            ns[r].x = cb ? s[r ^ tm].x : s[r].x;
            ns[r].y = cb ? s[r ^ tm].y : s[r].y;
        }
#pragma unroll
        for (int r = 0; r < 4; ++r) s[r] = ns[r];
    } else {                                    // both lane bits
        constexpr int cm = LM(C), tm = LM(T);
        const bool cb = (lane & cm) != 0;
#pragma unroll
        for (int r = 0; r < 4; ++r) {
            float px = shflx<tm>(s[r].x);
            float py = shflx<tm>(s[r].y);
            s[r].x = cb ? px : s[r].x;
            s[r].y = cb ? py : s[r].y;
        }
    }
}

// ---- ws layout (floats) ----
// [6*cc + 0..5]   rz c,s | ry c,s | ry2 c,s          (cc = 0..11)
// [72 + 8*pc ..]  pool U3: u00.re,im u01.re,im u10.re,im u11.re,im (pc=0..5)
// [120..139] W1   [140..149] b1   [150..159] W2   [160] b2
__global__ void qcnn_precompute(const float* __restrict__ conv_rz,
                                const float* __restrict__ conv_ry,
                                const float* __restrict__ conv_ry2,
                                const float* __restrict__ pool,
                                const float* __restrict__ W1,
                                const float* __restrict__ b1,
                                const float* __restrict__ W2,
                                const float* __restrict__ b2,
                                float* __restrict__ ws) {
    int t = threadIdx.x;
    if (t < 12) {
        float h;
        h = 0.5f * conv_rz[t];  ws[6*t+0] = cosf(h); ws[6*t+1] = sinf(h);
        h = 0.5f * conv_ry[t];  ws[6*t+2] = cosf(h); ws[6*t+3] = sinf(h);
        h = 0.5f * conv_ry2[t]; ws[6*t+4] = cosf(h); ws[6*t+5] = sinf(h);
    }
    if (t < 6) {
        float th = pool[3*t], ph = pool[3*t+1], la = pool[3*t+2];
        float ct = cosf(0.5f*th), st = sinf(0.5f*th);
        float* w = ws + 72 + 8*t;
        w[0] = ct;                 w[1] = 0.f;
        w[2] = -cosf(la)*st;       w[3] = -sinf(la)*st;
        w[4] = cosf(ph)*st;        w[5] = sinf(ph)*st;
        w[6] = cosf(ph+la)*ct;     w[7] = sinf(ph+la)*ct;
    }
    if (t < 20) ws[120 + t] = W1[t];
    if (t < 10) { ws[140 + t] = b1[t]; ws[150 + t] = W2[t]; }
    if (t == 0) ws[160] = b2[0];
}

// param fetch: lane-distributed VGPRs -> uniform scalar via readlane
__device__ __forceinline__ float pget(int i, float p0, float p1, float p2) {
    float src = (i < 64) ? p0 : ((i < 128) ? p1 : p2);
    return __uint_as_float(__builtin_amdgcn_readlane(__float_as_uint(src), i & 63));
}
#define P(I) pget((I), p0, p1, p2)

#define CONV(Q0, Q1, CC) do {                                                \
    sdiag<Q1, false>(s, lane);                       /* RZ(-pi/2) on q1 */   \
    cx<Q1, Q0>(s, lane);                                                     \
    rz_param<Q0>(s, lane, P(6*(CC)+0), P(6*(CC)+1));                         \
    ry<Q1>(s, lane, P(6*(CC)+2), P(6*(CC)+3));                               \
    cx<Q0, Q1>(s, lane);                                                     \
    ry<Q1>(s, lane, P(6*(CC)+4), P(6*(CC)+5));                               \
    cx<Q1, Q0>(s, lane);                                                     \
    sdiag<Q0, true>(s, lane);                        /* RZ(+pi/2) on q0 */   \
} while (0)

#define POOL(Q, PC) do {                                                     \
    u3g<Q>(s, lane,                                                          \
        c32{P(72+8*(PC)+0), P(72+8*(PC)+1)}, c32{P(72+8*(PC)+2), P(72+8*(PC)+3)}, \
        c32{P(72+8*(PC)+4), P(72+8*(PC)+5)}, c32{P(72+8*(PC)+6), P(72+8*(PC)+7)}); \
} while (0)

__device__ __forceinline__ float tanh_fast(float x) {
    float e = __expf(2.f * x);
    return (e - 1.f) / (e + 1.f);
}

__launch_bounds__(256)
__global__ void qcnn_main(const float* __restrict__ x,
                          const float* __restrict__ ws,
                          float* __restrict__ out, int B) {
    const int gid  = blockIdx.x * blockDim.x + threadIdx.x;
    const int b    = gid >> 6;
    const int lane = threadIdx.x & 63;
    if (b >= B) return;

    // one-time param pickup (3 coalesced dword loads)
    const float p0 = ws[lane];
    const float p1 = ws[lane + 64];
    const float p2 = ws[lane + 128];

    // --- angle encoding: product state ---
    const float4 xv0 = *reinterpret_cast<const float4*>(x + b * 8);
    const float4 xv1 = *reinterpret_cast<const float4*>(x + b * 8 + 4);
    const float xa[8] = {xv0.x, xv0.y, xv0.z, xv0.w, xv1.x, xv1.y, xv1.z, xv1.w};
    float cw[8], sw[8];
#pragma unroll
    for (int w = 0; w < 8; ++w) {
        float h = 0.5f * xa[w];
        cw[w] = __cosf(h); sw[w] = __sinf(h);
    }
    float a = (lane & LM(0)) ? sw[0] : cw[0];
    a *= (lane & LM(1)) ? sw[1] : cw[1];
    a *= (lane & LM(2)) ? sw[2] : cw[2];
    a *= (lane & LM(4)) ? sw[4] : cw[4];
    a *= (lane & LM(5)) ? sw[5] : cw[5];
    a *= (lane & LM(6)) ? sw[6] : cw[6];

    c32 s[4];
    s[0] = c32{a * cw[3] * cw[7], 0.f};   // r&2 -> q3 bit, r&1 -> q7 bit
    s[1] = c32{a * cw[3] * sw[7], 0.f};
    s[2] = c32{a * sw[3] * cw[7], 0.f};
    s[3] = c32{a * sw[3] * sw[7], 0.f};

    // --- layer 0 ---
    CONV(0,1,0); CONV(2,3,1); CONV(4,5,2); CONV(6,7,3);
    CONV(1,2,4); CONV(3,4,5); CONV(5,6,6);
    POOL(1,0); POOL(3,1); POOL(5,2); POOL(7,3);

    // --- layer 1 ---
    CONV(1,3,7); CONV(5,7,8); CONV(3,5,9);
    POOL(3,4); POOL(7,5);

    // --- expvals: Z on q3 (reg bit 2) and q7 (reg bit 1) ---
    float e3 = 0.f, e7 = 0.f;
#pragma unroll
    for (int r = 0; r < 4; ++r) {
        float p = s[r].x * s[r].x + s[r].y * s[r].y;
        e3 += (r & 2) ? -p : p;
        e7 += (r & 1) ? -p : p;
    }
    e3 = wave_sum(e3);
    e7 = wave_sum(e7);

    // --- MLP head ---
    float z = P(160);
#pragma unroll
    for (int i = 0; i < 10; ++i) {
        float h = tanh_fast(P(120 + 2*i) * e3 + P(121 + 2*i) * e7 + P(140 + i));
        z += P(150 + i) * h;
    }
    float o = 1.f / (1.f + __expf(-z));
    if (lane == 0) out[b] = o;
}

extern "C" void kernel_launch(void* const* d_in, const int* in_sizes, int n_in,
                              void* d_out, int out_size, void* d_ws, size_t ws_size,
                              hipStream_t stream) {
    const float* x       = (const float*)d_in[0];
    const float* conv_rz = (const float*)d_in[1];
    const float* conv_ry = (const float*)d_in[2];
    const float* conv_ry2= (const float*)d_in[3];
    const float* pool    = (const float*)d_in[4];
    const float* W1      = (const float*)d_in[5];
    const float* b1      = (const float*)d_in[6];
    const float* W2      = (const float*)d_in[7];
    const float* b2      = (const float*)d_in[8];
    float* out = (float*)d_out;
    float* ws  = (float*)d_ws;

    int B = in_sizes[0] / 8;

    qcnn_precompute<<<1, 64, 0, stream>>>(conv_rz, conv_ry, conv_ry2, pool,
                                          W1, b1, W2, b2, ws);

    int threads = 256;                      // 4 waves/block, 1 element/wave
    int blocks  = (B * 64 + threads - 1) / threads;
    qcnn_main<<<blocks, threads, 0, stream>>>(x, ws, out, B);
}

// Round 4
// 108.781 us; speedup vs baseline: 3.3393x; 2.0210x over previous
//
#include <hip/hip_runtime.h>
#include <math.h>

// ---------------------------------------------------------------------------
// QCNN 8-qubit statevector sim, v4: fused-conv + 16-lane-per-element layout.
// 4 elements per wave (16 lanes each), 16 c32 regs per lane = 256 amps.
// Qubit placement:
//   reg bits:  q1 -> 1, q3 -> 2, q5 -> 4, q7 -> 8   (hot + measured qubits)
//   lane bits: q2 -> 1 (DPP), q4 -> 2 (DPP), q6 -> 4 (swz), q0 -> 8 (swz)
// Each CONV block is algebraically fused to CX · CTRL-M · CX with M0/M1
// precomputed (RZ(theta), RZ(+-pi/2) folded in; dead diagonals dropped;
// trailing CX/S+ folded into following pool matrices).
// ---------------------------------------------------------------------------

struct c32 { float x, y; };
__device__ __forceinline__ c32 cmul(c32 a, c32 b){ return c32{a.x*b.x - a.y*b.y, a.x*b.y + a.y*b.x}; }
__device__ __forceinline__ c32 cadd(c32 a, c32 b){ return c32{a.x+b.x, a.y+b.y}; }
__device__ __forceinline__ c32 csel(bool c, c32 a, c32 b){ return c32{c?a.x:b.x, c?a.y:b.y}; }

struct PP { float a, b, c, d; };   // 256 lane-distributed param floats

__device__ __forceinline__ float pget(int i, PP pp) {
    float s = (i < 64) ? pp.a : (i < 128) ? pp.b : (i < 192) ? pp.c : pp.d;
    return __uint_as_float(__builtin_amdgcn_readlane(__float_as_uint(s), i & 63));
}
#define P(I) pget((I), pp)

// xor-shuffle across lanes, mask M (all within 16-lane groups)
template<int M>
__device__ __forceinline__ float sx(float v) {
    if constexpr (M == 1) {        // quad_perm [1,0,3,2]
        return __int_as_float(__builtin_amdgcn_update_dpp(
            __float_as_int(v), __float_as_int(v), 0xB1, 0xF, 0xF, false));
    } else if constexpr (M == 2) { // quad_perm [2,3,0,1]
        return __int_as_float(__builtin_amdgcn_update_dpp(
            __float_as_int(v), __float_as_int(v), 0x4E, 0xF, 0xF, false));
    } else if constexpr (M == 4) {
        return __int_as_float(__builtin_amdgcn_ds_swizzle(__float_as_int(v), 0x101F));
    } else {                       // M == 8
        return __int_as_float(__builtin_amdgcn_ds_swizzle(__float_as_int(v), 0x201F));
    }
}

// ---- conv type A: Q1 = reg qubit (mask RM), Q0 = lane qubit (mask LQ) ----
// CX_A(Q1->Q0); CTRLM (ctrl = lane Q0 bit, pairs along reg Q1); optional CX_D.
template<int RM, int LQ, bool KEEPD, int BASE>
__device__ __forceinline__ void conv_A(c32 s[16], int sub, PP pp) {
    #pragma unroll
    for (int r = 0; r < 16; ++r) if (r & RM) { s[r].x = sx<LQ>(s[r].x); s[r].y = sx<LQ>(s[r].y); }
    const bool cb = (sub & LQ) != 0;
    const c32 M00 = csel(cb, c32{P(BASE+8),P(BASE+9)},   c32{P(BASE+0),P(BASE+1)});
    const c32 M01 = csel(cb, c32{P(BASE+10),P(BASE+11)}, c32{P(BASE+2),P(BASE+3)});
    const c32 M10 = csel(cb, c32{P(BASE+12),P(BASE+13)}, c32{P(BASE+4),P(BASE+5)});
    const c32 M11 = csel(cb, c32{P(BASE+14),P(BASE+15)}, c32{P(BASE+6),P(BASE+7)});
    #pragma unroll
    for (int r = 0; r < 16; ++r) if (!(r & RM)) {
        c32 lo = s[r], hi = s[r|RM];
        s[r]    = cadd(cmul(M00,lo), cmul(M01,hi));
        s[r|RM] = cadd(cmul(M10,lo), cmul(M11,hi));
    }
    if constexpr (KEEPD) {
        #pragma unroll
        for (int r = 0; r < 16; ++r) if (r & RM) { s[r].x = sx<LQ>(s[r].x); s[r].y = sx<LQ>(s[r].y); }
    }
}

// ---- conv type B: Q0 = reg qubit (mask RM, control), Q1 = lane qubit (LQ) --
// CX_A(lane->reg): conditional reg-pair swap; CTRLM: M by reg bit (static),
// row by lane Q1 bit; CX_D folded into the following pool.
template<int RM, int LQ, int BASE>
__device__ __forceinline__ void conv_B(c32 s[16], int sub, PP pp) {
    const bool cb = (sub & LQ) != 0;
    #pragma unroll
    for (int r = 0; r < 16; ++r) if (!(r & RM)) {
        c32 lo = s[r], hi = s[r|RM];
        s[r]    = csel(cb, hi, lo);
        s[r|RM] = csel(cb, lo, hi);
    }
    const c32 RS0 = csel(cb, c32{P(BASE+6),P(BASE+7)},   c32{P(BASE+0),P(BASE+1)});
    const c32 RP0 = csel(cb, c32{P(BASE+4),P(BASE+5)},   c32{P(BASE+2),P(BASE+3)});
    const c32 RS1 = csel(cb, c32{P(BASE+14),P(BASE+15)}, c32{P(BASE+8),P(BASE+9)});
    const c32 RP1 = csel(cb, c32{P(BASE+12),P(BASE+13)}, c32{P(BASE+10),P(BASE+11)});
    #pragma unroll
    for (int r = 0; r < 16; ++r) {
        c32 pt{ sx<LQ>(s[r].x), sx<LQ>(s[r].y) };
        const c32 RS = (r & RM) ? RS1 : RS0;
        const c32 RP = (r & RM) ? RP1 : RP0;
        s[r] = cadd(cmul(RS, s[r]), cmul(RP, pt));
    }
}

// ---- conv reg-reg: ctrl reg mask CM (Q0), target reg mask TM (Q1) ----
template<int CM, int TM, bool KEEPD, int BASE>
__device__ __forceinline__ void conv_RR(c32 s[16], PP pp) {
    c32 m[2][2][2];
    #pragma unroll
    for (int q = 0; q < 2; ++q)
      #pragma unroll
      for (int i = 0; i < 2; ++i)
        #pragma unroll
        for (int j = 0; j < 2; ++j)
          m[q][i][j] = c32{ P(BASE + q*8 + i*4 + j*2), P(BASE + q*8 + i*4 + j*2 + 1) };
    #pragma unroll
    for (int r = 0; r < 16; ++r) if ((r & TM) && !(r & CM)) { c32 t = s[r]; s[r] = s[r|CM]; s[r|CM] = t; }
    #pragma unroll
    for (int r = 0; r < 16; ++r) if (!(r & TM)) {
        const int q = (r & CM) ? 1 : 0;
        c32 lo = s[r], hi = s[r|TM];
        s[r]    = cadd(cmul(m[q][0][0],lo), cmul(m[q][0][1],hi));
        s[r|TM] = cadd(cmul(m[q][1][0],lo), cmul(m[q][1][1],hi));
    }
    if constexpr (KEEPD) {
        #pragma unroll
        for (int r = 0; r < 16; ++r) if ((r & TM) && !(r & CM)) { c32 t = s[r]; s[r] = s[r|CM]; s[r|CM] = t; }
    }
}

// ---- pools (all on reg qubits) ----
template<int RM, int BASE>
__device__ __forceinline__ void pool_plain(c32 s[16], PP pp) {
    const c32 V00{P(BASE+0),P(BASE+1)}, V01{P(BASE+2),P(BASE+3)};
    const c32 V10{P(BASE+4),P(BASE+5)}, V11{P(BASE+6),P(BASE+7)};
    #pragma unroll
    for (int r = 0; r < 16; ++r) if (!(r & RM)) {
        c32 lo = s[r], hi = s[r|RM];
        s[r]    = cadd(cmul(V00,lo), cmul(V01,hi));
        s[r|RM] = cadd(cmul(V10,lo), cmul(V11,hi));
    }
}
// pool with folded CX_D controlled by LANE bit LQ: V or V*X (column swap)
template<int RM, int LQ, int BASE>
__device__ __forceinline__ void pool_lanec(c32 s[16], int sub, PP pp) {
    const bool cb = (sub & LQ) != 0;
    const c32 E00 = csel(cb, c32{P(BASE+2),P(BASE+3)}, c32{P(BASE+0),P(BASE+1)});
    const c32 E01 = csel(cb, c32{P(BASE+0),P(BASE+1)}, c32{P(BASE+2),P(BASE+3)});
    const c32 E10 = csel(cb, c32{P(BASE+6),P(BASE+7)}, c32{P(BASE+4),P(BASE+5)});
    const c32 E11 = csel(cb, c32{P(BASE+4),P(BASE+5)}, c32{P(BASE+6),P(BASE+7)});
    #pragma unroll
    for (int r = 0; r < 16; ++r) if (!(r & RM)) {
        c32 lo = s[r], hi = s[r|RM];
        s[r]    = cadd(cmul(E00,lo), cmul(E01,hi));
        s[r|RM] = cadd(cmul(E10,lo), cmul(E11,hi));
    }
}
// pool with folded CX_D controlled by REG bit CRM (compile-time column swap)
template<int RM, int CRM, int BASE>
__device__ __forceinline__ void pool_regc(c32 s[16], PP pp) {
    const c32 V00{P(BASE+0),P(BASE+1)}, V01{P(BASE+2),P(BASE+3)};
    const c32 V10{P(BASE+4),P(BASE+5)}, V11{P(BASE+6),P(BASE+7)};
    #pragma unroll
    for (int r = 0; r < 16; ++r) if (!(r & RM)) {
        const bool swp = (r & CRM) != 0;                 // compile-time
        const c32 A = swp ? V01 : V00, Bm = swp ? V00 : V01;
        const c32 C = swp ? V11 : V10, D  = swp ? V10 : V11;
        c32 lo = s[r], hi = s[r|RM];
        s[r]    = cadd(cmul(A,lo),  cmul(Bm,hi));
        s[r|RM] = cadd(cmul(C,lo),  cmul(D,hi));
    }
}

// ---- ws layout (floats) ----
// [16*cc .. +15]  cc=0..9: M0 (8: 00x,00y,01x,01y,10x,10y,11x,11y), M1 (8)
// [160 + 8*pc]    pc=0..5: pool V (8)
// [208..227] W1  [228..237] b1  [238..247] W2  [248] b2
__global__ void qcnn_setup(const float* __restrict__ rz,  const float* __restrict__ ry,
                           const float* __restrict__ ry2, const float* __restrict__ pool,
                           const float* __restrict__ W1,  const float* __restrict__ b1,
                           const float* __restrict__ W2,  const float* __restrict__ b2,
                           float* __restrict__ ws) {
    if (threadIdx.x != 0 || blockIdx.x != 0) return;
    const bool hasD[10] = {true,true,true,true,false,false,false,true,true,false};
    for (int cc = 0; cc < 10; ++cc) {
        float tz = rz[cc], ta = ry[cc], tb = ry2[cc];
        float cz = cosf(0.5f*tz), sz = sinf(0.5f*tz);
        float cp = cosf(0.5f*(ta+tb)), sp = sinf(0.5f*(ta+tb));
        float cm = cosf(0.5f*(ta-tb)), sm = sinf(0.5f*(ta-tb));
        float A0[2][2] = {{cp,-sp},{sp,cp}};        // RY(b)*RY(a)
        float A1[2][2] = {{sm,cm},{cm,-sm}};        // RY(b)*X*RY(a)
        float* o = ws + 16*cc;
        for (int which = 0; which < 2; ++which) {
            float px = cz, py = which ? sz : -sz;   // e^{+-i tz/2}
            for (int row = 0; row < 2; ++row)
              for (int col = 0; col < 2; ++col) {
                float ex = which ? A1[row][col] : A0[row][col], ey = 0.f;
                if (hasD[cc] && col == 1) { ey = -ex; ex = 0.f; }   // * (-i): S- fold
                o[which*8 + row*4 + col*2 + 0] = px*ex - py*ey;
                o[which*8 + row*4 + col*2 + 1] = px*ey + py*ex;
            }
        }
    }
    const bool hasS[6] = {true,true,true,false,true,false};
    for (int pc = 0; pc < 6; ++pc) {
        float th = pool[3*pc], ph = pool[3*pc+1], la = pool[3*pc+2];
        float ct = cosf(0.5f*th), st = sinf(0.5f*th);
        float u[2][2][2] = {
            {{ct, 0.f},           {-cosf(la)*st, -sinf(la)*st}},
            {{cosf(ph)*st, sinf(ph)*st}, {cosf(ph+la)*ct, sinf(ph+la)*ct}}};
        if (hasS[pc]) {   // col1 *= i : (x,y) -> (-y, x)   (S+ fold)
            for (int row = 0; row < 2; ++row) {
                float xx = u[row][1][0], yy = u[row][1][1];
                u[row][1][0] = -yy; u[row][1][1] = xx;
            }
        }
        float* o = ws + 160 + 8*pc;
        for (int row = 0; row < 2; ++row) for (int col = 0; col < 2; ++col) {
            o[row*4+col*2+0] = u[row][col][0];
            o[row*4+col*2+1] = u[row][col][1];
        }
    }
    for (int i = 0; i < 20; ++i) ws[208+i] = W1[i];
    for (int i = 0; i < 10; ++i) { ws[228+i] = b1[i]; ws[238+i] = W2[i]; }
    ws[248] = b2[0];
}

__device__ __forceinline__ float tanh_fast(float x) {
    float e = __expf(2.f * x);
    return (e - 1.f) / (e + 1.f);
}

__launch_bounds__(256)
__global__ void qcnn_main(const float* __restrict__ x, const float* __restrict__ ws,
                          float* __restrict__ out, int B) {
    const int lane  = threadIdx.x & 63;
    const int sub   = lane & 15;
    const int gwave = (blockIdx.x * blockDim.x + threadIdx.x) >> 6;
    const int b     = gwave * 4 + (lane >> 4);
    if (b >= B) return;

    int i3 = lane + 192; if (i3 > 248) i3 = 248;      // stay in written range
    PP pp{ ws[lane], ws[lane+64], ws[lane+128], ws[i3] };

    // --- angle-encoding product state ---
    const float4 xv0 = *reinterpret_cast<const float4*>(x + b*8);
    const float4 xv1 = *reinterpret_cast<const float4*>(x + b*8 + 4);
    const float xa[8] = {xv0.x, xv0.y, xv0.z, xv0.w, xv1.x, xv1.y, xv1.z, xv1.w};
    float cw[8], sw_[8];
    #pragma unroll
    for (int w = 0; w < 8; ++w) { float h = 0.5f*xa[w]; cw[w] = __cosf(h); sw_[w] = __sinf(h); }

    float fl = ((sub & 1) ? sw_[2] : cw[2]) * ((sub & 2) ? sw_[4] : cw[4])
             * ((sub & 4) ? sw_[6] : cw[6]) * ((sub & 8) ? sw_[0] : cw[0]);
    float a13[4] = {cw[1]*cw[3], sw_[1]*cw[3], cw[1]*sw_[3], sw_[1]*sw_[3]};  // idx: q1|q3<<1
    float a57[4] = {cw[5]*cw[7], sw_[5]*cw[7], cw[5]*sw_[7], sw_[5]*sw_[7]};  // idx: q5|q7<<1

    c32 s[16];
    #pragma unroll
    for (int r = 0; r < 16; ++r) s[r] = c32{ fl * a13[r & 3] * a57[r >> 2], 0.f };

    // --- layer 0, phase 1: (0,1) (2,3) (4,5) (6,7) ---
    conv_A<1, 8, false,  0>(s, sub, pp);   // cc0: Q1=q1(reg1), Q0=q0(lane8); CX_D dropped
    conv_A<2, 1, true,  16>(s, sub, pp);   // cc1: q3 / q2
    conv_A<4, 2, true,  32>(s, sub, pp);   // cc2: q5 / q4
    conv_A<8, 4, true,  48>(s, sub, pp);   // cc3: q7 / q6
    // --- layer 0, phase 2: (1,2) (3,4) (5,6) --- (CX_D folded into pools)
    conv_B<1, 1, 64>(s, sub, pp);          // cc4: Q0=q1(reg1), Q1=q2(lane1)
    conv_B<2, 2, 80>(s, sub, pp);          // cc5: q3 / q4
    conv_B<4, 4, 96>(s, sub, pp);          // cc6: q5 / q6
    // --- layer-0 pools ---
    pool_lanec<1, 1, 160>(s, sub, pp);     // pc0 on q1, V*X^{q2}
    pool_lanec<2, 2, 168>(s, sub, pp);     // pc1 on q3, V*X^{q4}
    pool_lanec<4, 4, 176>(s, sub, pp);     // pc2 on q5, V*X^{q6}
    pool_plain<8, 184>(s, pp);             // pc3 on q7
    // --- layer 1: (1,3) (5,7) (3,5), all reg-reg ---
    conv_RR<1, 2, false, 112>(s, pp);      // cc7: ctrl q1, tgt q3; CX_D dropped
    conv_RR<4, 8, true,  128>(s, pp);      // cc8: ctrl q5, tgt q7
    conv_RR<2, 4, false, 144>(s, pp);      // cc9: ctrl q3, tgt q5; CX_D -> pc4
    // --- layer-1 pools ---
    pool_regc<2, 4, 192>(s, pp);           // pc4 on q3, V*X^{q5} (reg, static)
    pool_plain<8, 200>(s, pp);             // pc5 on q7

    // --- expvals: Z on q3 (r&2) and q7 (r&8) ---
    float e3 = 0.f, e7 = 0.f;
    #pragma unroll
    for (int r = 0; r < 16; ++r) {
        float p = s[r].x*s[r].x + s[r].y*s[r].y;
        e3 += (r & 2) ? -p : p;
        e7 += (r & 8) ? -p : p;
    }
    e3 += sx<1>(e3); e3 += sx<2>(e3); e3 += sx<4>(e3); e3 += sx<8>(e3);
    e7 += sx<1>(e7); e7 += sx<2>(e7); e7 += sx<4>(e7); e7 += sx<8>(e7);

    // --- MLP head (all lanes compute; lanes differ only across elements) ---
    float z = P(248);
    #pragma unroll
    for (int i = 0; i < 10; ++i) {
        float h = tanh_fast(P(208+2*i)*e3 + P(209+2*i)*e7 + P(228+i));
        z += P(238+i)*h;
    }
    float o = 1.f / (1.f + __expf(-z));
    if (sub == 0) out[b] = o;
}

extern "C" void kernel_launch(void* const* d_in, const int* in_sizes, int n_in,
                              void* d_out, int out_size, void* d_ws, size_t ws_size,
                              hipStream_t stream) {
    const float* x       = (const float*)d_in[0];
    const float* conv_rz = (const float*)d_in[1];
    const float* conv_ry = (const float*)d_in[2];
    const float* conv_ry2= (const float*)d_in[3];
    const float* pool    = (const float*)d_in[4];
    const float* W1      = (const float*)d_in[5];
    const float* b1      = (const float*)d_in[6];
    const float* W2      = (const float*)d_in[7];
    const float* b2      = (const float*)d_in[8];
    float* out = (float*)d_out;
    float* ws  = (float*)d_ws;

    int B = in_sizes[0] / 8;

    qcnn_setup<<<1, 1, 0, stream>>>(conv_rz, conv_ry, conv_ry2, pool,
                                    W1, b1, W2, b2, ws);

    int blocks = (B + 15) / 16;            // 16 elements per 256-thread block
    qcnn_main<<<blocks, 256, 0, stream>>>(x, ws, out, B);
}